// Round 1
// baseline (430.729 us; speedup 1.0000x reference)
//
#include <hip/hip_runtime.h>
#include <hip/hip_bf16.h>

// Problem constants (from reference)
#define B_SZ   2
#define N_IN   163842
#define N_OUT  40962
#define C_DIM  128
#define K_CAND 7
// 1/(2*SIGMA^2), SIGMA=0.4
#define INV_2SIG2 3.125f

typedef float f32x4 __attribute__((ext_vector_type(4)));

__device__ __forceinline__ float bf2f(unsigned short u) {
    return __uint_as_float((unsigned)u << 16);
}
__device__ __forceinline__ unsigned short f2bf(float f) {
    // RNE, matches __float2bfloat16 for non-NaN inputs
    unsigned u = __float_as_uint(f);
    return (unsigned short)((u + 0x7fffu + ((u >> 16) & 1u)) >> 16);
}

// ---------- Pass A: count children per parent ----------
__global__ __launch_bounds__(256) void count_kernel(
    const int* __restrict__ parent, int* __restrict__ count)
{
    int n = blockIdx.x * 256 + threadIdx.x;
    if (n < N_IN) atomicAdd(&count[parent[n]], 1);
}

// ---------- Pass B: single-block exclusive scan of 40962 counts ----------
#define SCAN_T 1024
#define PER_T  41   // 1024*41 = 41984 >= 40962
__global__ __launch_bounds__(SCAN_T) void scan_kernel(
    const int* __restrict__ count, int* __restrict__ offs)
{
    __shared__ int sh[SCAN_T];
    const int t = threadIdx.x;
    const int base = t * PER_T;
    int local[PER_T];
    int sum = 0;
    #pragma unroll
    for (int i = 0; i < PER_T; ++i) {
        const int j = base + i;
        const int c = (j < N_OUT) ? count[j] : 0;
        local[i] = sum;          // thread-local exclusive prefix
        sum += c;
    }
    sh[t] = sum;
    __syncthreads();
    for (int off = 1; off < SCAN_T; off <<= 1) {
        int v = (t >= off) ? sh[t - off] : 0;
        __syncthreads();
        sh[t] += v;
        __syncthreads();
    }
    const int ebase = sh[t] - sum;   // exclusive base for this thread's chunk
    #pragma unroll
    for (int i = 0; i < PER_T; ++i) {
        const int j = base + i;
        if (j < N_OUT) offs[j] = ebase + local[i];
    }
}

// ---------- Pass C: fill permutation (CSR child lists) ----------
// atomicSub on count doubles as the cursor (any within-parent order is fine).
__global__ __launch_bounds__(256) void fill_kernel(
    const int* __restrict__ parent, const int* __restrict__ offs,
    int* __restrict__ count, int* __restrict__ perm)
{
    int n = blockIdx.x * 256 + threadIdx.x;
    if (n < N_IN) {
        const int p = parent[n];
        const int pos = offs[p] + atomicSub(&count[p], 1) - 1;
        perm[pos] = n;
    }
}

// ---------- Pass D: per-parent reduce, normalize, store bf16 ----------
// One 64-lane wave per parent. Lanes 0-31 accumulate batch 0, lanes 32-63
// batch 1 (each lane owns 4 channels = one float4). Child ids+omegas are
// loaded coalesced 64-at-a-time and broadcast via shfl, so all x-row loads
// in the inner loop are independent (deep MLP, no per-child dependent chain).
__global__ __launch_bounds__(256) void reduce_kernel(
    const float* __restrict__ x,       // (B, N_IN, C)
    const float* __restrict__ omega,   // (N_IN,)
    const int*   __restrict__ offs,
    const int*   __restrict__ perm,
    __hip_bfloat16* __restrict__ down) // (B, N_OUT, C) normalized
{
    const int wid  = threadIdx.x >> 6;           // wave in block: 0..3
    const int lane = threadIdx.x & 63;
    const int p = blockIdx.x * 4 + wid;
    if (p >= N_OUT) return;

    const int beg = offs[p];
    const int end = (p + 1 < N_OUT) ? offs[p + 1] : N_IN;
    const int cnt = end - beg;

    const int half = lane >> 5;                  // batch index
    const int l    = lane & 31;                  // float4 channel group
    const f32x4* x4 = (const f32x4*)x;
    const size_t bofs = (size_t)half * N_IN * 32;

    f32x4 acc = {0.f, 0.f, 0.f, 0.f};
    float ds = 0.f;

    for (int cbase = 0; cbase < cnt; cbase += 64) {
        const int m = min(64, cnt - cbase);
        int   myn  = 0;
        float myom = 0.f;
        if (lane < m) {
            myn  = perm[beg + cbase + lane];
            myom = omega[myn];
        }
        for (int j = 0; j < m; ++j) {
            const int   n  = __shfl(myn,  j);
            const float om = __shfl(myom, j);
            ds += om;
            const f32x4 v = __builtin_nontemporal_load(&x4[bofs + (size_t)n * 32 + l]);
            acc.x = fmaf(v.x, om, acc.x);
            acc.y = fmaf(v.y, om, acc.y);
            acc.z = fmaf(v.z, om, acc.z);
            acc.w = fmaf(v.w, om, acc.w);
        }
    }
    const float inv = 1.f / fmaxf(ds, 1e-8f);

    ushort4 hh;
    hh.x = f2bf(acc.x * inv);
    hh.y = f2bf(acc.y * inv);
    hh.z = f2bf(acc.z * inv);
    hh.w = f2bf(acc.w * inv);
    ((ushort4*)down)[((size_t)half * N_OUT + p) * 32 + l] = hh;
}

// ---------- Pass E: weighted gather ----------
// One 64-lane wave per n: lanes 0-31 batch 0, lanes 32-63 batch 1, each lane
// owns 4 channels (ushort4 loads from down, float4 nontemporal stores to out).
// K=7 weights computed in lanes 0-6, reduced + broadcast via shfl (no LDS).
__global__ __launch_bounds__(256) void gather_kernel(
    const float* __restrict__ delta,     // (N_IN, K)
    const float* __restrict__ cand_mask, // (N_IN, K)
    const int*   __restrict__ cand_idx,  // (N_IN, K)
    const __hip_bfloat16* __restrict__ down, // (B, N_OUT, C) normalized
    float* __restrict__ out)             // (B, N_IN, C)
{
    const int wid  = threadIdx.x >> 6;   // 0..3
    const int lane = threadIdx.x & 63;
    const int n = blockIdx.x * 4 + wid;
    if (n >= N_IN) return;

    float w = 0.f;
    int pidx = 0;
    if (lane < K_CAND) {
        const float d   = __builtin_nontemporal_load(&delta[(size_t)n * K_CAND + lane]);
        const float msk = __builtin_nontemporal_load(&cand_mask[(size_t)n * K_CAND + lane]);
        pidx = __builtin_nontemporal_load(&cand_idx[(size_t)n * K_CAND + lane]);
        w = __expf(-d * d * INV_2SIG2) * msk;
    }
    // sum w over lanes 0..6 (lane 7 holds 0) within each 8-lane group
    float s = w;
    s += __shfl_xor(s, 1);
    s += __shfl_xor(s, 2);
    s += __shfl_xor(s, 4);
    const float coef = w / fmaxf(s, 1e-8f);

    const int half = lane >> 5;
    const int l    = lane & 31;
    const ushort4* d4 = (const ushort4*)down;
    const size_t bofs = (size_t)half * N_OUT * 32;

    f32x4 acc = {0.f, 0.f, 0.f, 0.f};
    #pragma unroll
    for (int k = 0; k < K_CAND; ++k) {
        const float cf = __shfl(coef, k);
        const int   p  = __shfl(pidx, k);
        const ushort4 v = d4[bofs + (size_t)p * 32 + l];
        acc.x = fmaf(cf, bf2f(v.x), acc.x);
        acc.y = fmaf(cf, bf2f(v.y), acc.y);
        acc.z = fmaf(cf, bf2f(v.z), acc.z);
        acc.w = fmaf(cf, bf2f(v.w), acc.w);
    }
    f32x4* o4 = (f32x4*)out;
    __builtin_nontemporal_store(acc, &o4[((size_t)half * N_IN + n) * 32 + l]);
}

extern "C" void kernel_launch(void* const* d_in, const int* in_sizes, int n_in,
                              void* d_out, int out_size, void* d_ws, size_t ws_size,
                              hipStream_t stream) {
    const float* x         = (const float*)d_in[0];
    const float* omega     = (const float*)d_in[1];
    const float* delta     = (const float*)d_in[2];
    const float* cand_mask = (const float*)d_in[3];
    const int*   parent    = (const int*)d_in[4];
    const int*   cand_idx  = (const int*)d_in[5];
    float* out = (float*)d_out;

    // workspace: down bf16 | count | offs | perm
    __hip_bfloat16* down = (__hip_bfloat16*)d_ws;
    int* count = (int*)(down + (size_t)B_SZ * N_OUT * C_DIM);
    int* offs  = count + N_OUT;
    int* perm  = offs + N_OUT;

    // zero count only (164 KB)
    hipMemsetAsync(count, 0, (size_t)N_OUT * sizeof(int), stream);

    const int nblk = (N_IN + 255) / 256;
    count_kernel<<<nblk, 256, 0, stream>>>(parent, count);
    scan_kernel<<<1, SCAN_T, 0, stream>>>(count, offs);
    fill_kernel<<<nblk, 256, 0, stream>>>(parent, offs, count, perm);
    reduce_kernel<<<(N_OUT + 3) / 4, 256, 0, stream>>>(x, omega, offs, perm, down);
    gather_kernel<<<(N_IN + 3) / 4, 256, 0, stream>>>(
        delta, cand_mask, cand_idx, down, out);
}